// Round 1
// baseline (384.059 us; speedup 1.0000x reference)
//
#include <hip/hip_runtime.h>
#include <stdint.h>

// ---------------------------------------------------------------------------
// FlatLinear: y[b,s,o] = sum_i x[b,s,i] * centroids[labels[o*4096+i]] + bias[o]
// M = 8192 (=4*2048), N = 4096 (out), K = 4096 (in).
// Strategy: dequant W -> bf16 (ws), cast x -> bf16 (ws), then bf16 MFMA GEMM
// (m97 structure: 128x128 tile, BK=32, global_load_lds width-16 staging).
// ---------------------------------------------------------------------------

typedef __attribute__((ext_vector_type(8))) short  bf16x8;
typedef __attribute__((ext_vector_type(4))) float  f32x4;
typedef __attribute__((ext_vector_type(4))) int    i32x4;
typedef __attribute__((ext_vector_type(8))) ushort u16x8;
typedef __attribute__((ext_vector_type(4))) float  fvec4;

#define K_DIM 4096
#define N_DIM 4096

__device__ __forceinline__ ushort f2bf(float f) {
  // round-to-nearest-even bf16 truncation (no NaN handling needed here)
  uint32_t u = __float_as_uint(f);
  return (ushort)((u + 0x7fffu + ((u >> 16) & 1u)) >> 16);
}

__device__ __forceinline__ void async16(const void* g, void* l) {
  __builtin_amdgcn_global_load_lds(
      (const __attribute__((address_space(1))) void*)g,
      (__attribute__((address_space(3))) void*)l, 16, 0, 0);
}

// --------------------------- dequant: labels -> bf16 W ---------------------
__global__ __launch_bounds__(256) void dequant_w(const int* __restrict__ labels,
                                                 const float* __restrict__ cent,
                                                 ushort* __restrict__ wb, int n) {
  __shared__ ushort cb[256];
  cb[threadIdx.x] = f2bf(cent[threadIdx.x]);
  __syncthreads();
  const int stride = gridDim.x * 256 * 8;
  for (int i = ((int)blockIdx.x * 256 + (int)threadIdx.x) * 8; i < n; i += stride) {
    i32x4 l0 = *(const i32x4*)(labels + i);
    i32x4 l1 = *(const i32x4*)(labels + i + 4);
    u16x8 w;
    w[0] = cb[l0[0]]; w[1] = cb[l0[1]]; w[2] = cb[l0[2]]; w[3] = cb[l0[3]];
    w[4] = cb[l1[0]]; w[5] = cb[l1[1]]; w[6] = cb[l1[2]]; w[7] = cb[l1[3]];
    *(u16x8*)(wb + i) = w;
  }
}

// --------------------------- cast: x fp32 -> bf16 ---------------------------
__global__ __launch_bounds__(256) void cvt_x(const float* __restrict__ x,
                                             ushort* __restrict__ xb, int n) {
  const int stride = gridDim.x * 256 * 8;
  for (int i = ((int)blockIdx.x * 256 + (int)threadIdx.x) * 8; i < n; i += stride) {
    fvec4 a = *(const fvec4*)(x + i);
    fvec4 b = *(const fvec4*)(x + i + 4);
    u16x8 w;
    w[0] = f2bf(a[0]); w[1] = f2bf(a[1]); w[2] = f2bf(a[2]); w[3] = f2bf(a[3]);
    w[4] = f2bf(b[0]); w[5] = f2bf(b[1]); w[6] = f2bf(b[2]); w[7] = f2bf(b[3]);
    *(u16x8*)(xb + i) = w;
  }
}

// --------------------------- bf16 MFMA GEMM (m97 structure) -----------------
// C[M][N] = A[M][K] * B[N][K]^T + bias, 128x128 tile, BK=32, 4 waves (2x2),
// each wave 64x64 out = 4x4 frags of 16x16x32.
__global__ __launch_bounds__(256, 2) void gemm_bf16(
    const ushort* __restrict__ A,   // [M][K] bf16 bits (x)
    const ushort* __restrict__ B,   // [N][K] bf16 bits (W)
    const float* __restrict__ bias, // [N]
    float* __restrict__ C) {
  __shared__ ushort As[128 * 32];
  __shared__ ushort Bs[128 * 32];

  const int tid = threadIdx.x;
  const int wid = tid >> 6;
  const int lane = tid & 63;

  // bijective XCD-aware swizzle (m204 variant)
  const int nwg = gridDim.x;
  const int bid = blockIdx.x;
  const int q = nwg >> 3, r = nwg & 7;
  const int xcd = bid & 7, sub = bid >> 3;
  const int swz = (xcd < r ? xcd * (q + 1) : r * (q + 1) + (xcd - r) * q) + sub;

  const int gn = N_DIM / 128;  // 32
  const int bm = swz / gn, bn = swz % gn;

  const long aBase = (long)bm * 128 * K_DIM;
  const long bBase = (long)bn * 128 * K_DIM;

  // staging: 8 chunks of 16 rows x 32 cols; wave w owns chunks 2w, 2w+1.
  // lane -> (row = lane/4, col = (lane&3)*8) within a chunk; LDS dest is
  // wave-uniform base (HW adds lane*16 bytes).
  const int srow = lane >> 2;
  const int scol = (lane & 3) * 8;
  const int ch0 = wid * 2;

  const ushort* gA0 = A + aBase + (long)(ch0 * 16 + srow) * K_DIM + scol;
  const ushort* gA1 = gA0 + (long)16 * K_DIM;
  const ushort* gB0 = B + bBase + (long)(ch0 * 16 + srow) * K_DIM + scol;
  const ushort* gB1 = gB0 + (long)16 * K_DIM;
  ushort* lA0 = &As[ch0 * 512];
  ushort* lA1 = &As[ch0 * 512 + 512];
  ushort* lB0 = &Bs[ch0 * 512];
  ushort* lB1 = &Bs[ch0 * 512 + 512];

  const int wr = (wid >> 1) * 64;   // wave row offset in tile
  const int wc = (wid & 1) * 64;    // wave col offset in tile
  const int l15 = lane & 15;
  const int kch = (lane >> 4) * 8;  // k-chunk within BK=32

  f32x4 acc[4][4];
#pragma unroll
  for (int i = 0; i < 4; ++i)
#pragma unroll
    for (int j = 0; j < 4; ++j) acc[i][j] = (f32x4){0.f, 0.f, 0.f, 0.f};

  for (int kt = 0; kt < K_DIM; kt += 32) {
    async16(gA0 + kt, lA0);
    async16(gA1 + kt, lA1);
    async16(gB0 + kt, lB0);
    async16(gB1 + kt, lB1);
    __syncthreads();  // drains vmcnt before any wave reads LDS

    bf16x8 af[4], bfr[4];
#pragma unroll
    for (int i = 0; i < 4; ++i)
      af[i] = *(const bf16x8*)&As[(wr + i * 16 + l15) * 32 + kch];
#pragma unroll
    for (int j = 0; j < 4; ++j)
      bfr[j] = *(const bf16x8*)&Bs[(wc + j * 16 + l15) * 32 + kch];
#pragma unroll
    for (int i = 0; i < 4; ++i)
#pragma unroll
      for (int j = 0; j < 4; ++j)
        acc[i][j] = __builtin_amdgcn_mfma_f32_16x16x32_bf16(af[i], bfr[j],
                                                            acc[i][j], 0, 0, 0);
    __syncthreads();  // before next iteration overwrites LDS
  }

  // epilogue: C/D layout col = lane&15, row = (lane>>4)*4 + reg
  float bv[4];
#pragma unroll
  for (int j = 0; j < 4; ++j) bv[j] = bias[bn * 128 + wc + j * 16 + l15];

  float* Cp = C + (long)(bm * 128) * N_DIM + bn * 128;
  const int rbase = (lane >> 4) * 4;
#pragma unroll
  for (int i = 0; i < 4; ++i)
#pragma unroll
    for (int rr = 0; rr < 4; ++rr) {
      const long row = wr + i * 16 + rbase + rr;
      float* cr = Cp + row * N_DIM;
#pragma unroll
      for (int j = 0; j < 4; ++j)
        cr[wc + j * 16 + l15] = acc[i][j][rr] + bv[j];
    }
}

// --------------------------- naive fallback (ws too small) ------------------
__global__ void naive_kernel(const float* __restrict__ x,
                             const float* __restrict__ cent,
                             const int* __restrict__ labels,
                             const float* __restrict__ bias,
                             float* __restrict__ out, int M) {
  __shared__ float cb[256];
  if (threadIdx.x < 256) cb[threadIdx.x] = cent[threadIdx.x];
  __syncthreads();
  long o = (long)blockIdx.x * blockDim.x + threadIdx.x;
  if (o >= (long)M * N_DIM) return;
  int n = (int)(o % N_DIM);
  long m = o / N_DIM;
  const float* xr = x + m * K_DIM;
  const int* lr = labels + (long)n * K_DIM;
  float s = 0.f;
  for (int k = 0; k < K_DIM; ++k) s += xr[k] * cb[lr[k]];
  out[o] = s + bias[n];
}

// ---------------------------------------------------------------------------
extern "C" void kernel_launch(void* const* d_in, const int* in_sizes, int n_in,
                              void* d_out, int out_size, void* d_ws, size_t ws_size,
                              hipStream_t stream) {
  const float* x      = (const float*)d_in[0];
  const float* cent   = (const float*)d_in[1];
  const int*   labels = (const int*)d_in[2];
  const float* bias   = (const float*)d_in[3];
  float* out = (float*)d_out;

  const int xN = in_sizes[0];      // M*K
  const int M  = xN / K_DIM;       // 8192
  const int wN = in_sizes[2];      // N*K

  const size_t need = (size_t)wN * 2 + (size_t)xN * 2;  // 96 MB
  if (ws_size < need || (M % 128) != 0) {
    long total = (long)M * N_DIM;
    int blocks = (int)((total + 255) / 256);
    naive_kernel<<<blocks, 256, 0, stream>>>(x, cent, labels, bias, out, M);
    return;
  }

  ushort* wb = (ushort*)d_ws;      // [N][K] bf16
  ushort* xb = wb + (size_t)wN;    // [M][K] bf16

  dequant_w<<<2048, 256, 0, stream>>>(labels, cent, wb, wN);
  cvt_x<<<2048, 256, 0, stream>>>(x, xb, xN);

  const int grid = (M / 128) * (N_DIM / 128);  // 2048
  gemm_bf16<<<grid, 256, 0, stream>>>(xb, wb, bias, out);
}

// Round 2
// 352.064 us; speedup vs baseline: 1.0909x; 1.0909x over previous
//
#include <hip/hip_runtime.h>
#include <stdint.h>

// ---------------------------------------------------------------------------
// FlatLinear: y = x @ W^T + bias, W = centroids[labels] (4096x4096, K=256 cb)
// M=8192, N=4096, K=4096.  dequant W->bf16, cast x->bf16, then 256x256-tile
// 8-phase bf16 MFMA GEMM (BK=64, 8 waves, counted vmcnt, XOR-swizzled LDS).
// ---------------------------------------------------------------------------

typedef __attribute__((ext_vector_type(8))) short  bf16x8;
typedef __attribute__((ext_vector_type(4))) float  f32x4;
typedef __attribute__((ext_vector_type(4))) int    i32x4;
typedef __attribute__((ext_vector_type(8))) ushort u16x8;
typedef __attribute__((ext_vector_type(4))) float  fvec4;

#define K_DIM 4096
#define N_DIM 4096
#define NT    (K_DIM / 64)   // 64 K-tiles of BK=64

__device__ __forceinline__ ushort f2bf(float f) {
  uint32_t u = __float_as_uint(f);
  return (ushort)((u + 0x7fffu + ((u >> 16) & 1u)) >> 16);
}

__device__ __forceinline__ void async16(const ushort* g, ushort* l) {
  __builtin_amdgcn_global_load_lds(
      (const __attribute__((address_space(1))) void*)g,
      (__attribute__((address_space(3))) void*)l, 16, 0, 0);
}

// --------------------------- dequant: labels -> bf16 W ---------------------
__global__ __launch_bounds__(256) void dequant_w(const int* __restrict__ labels,
                                                 const float* __restrict__ cent,
                                                 ushort* __restrict__ wb, int n) {
  __shared__ ushort cb[256];
  cb[threadIdx.x] = f2bf(cent[threadIdx.x]);
  __syncthreads();
  const int stride = gridDim.x * 256 * 8;
  for (int i = ((int)blockIdx.x * 256 + (int)threadIdx.x) * 8; i < n; i += stride) {
    i32x4 l0 = *(const i32x4*)(labels + i);
    i32x4 l1 = *(const i32x4*)(labels + i + 4);
    u16x8 w;
    w[0] = cb[l0[0]]; w[1] = cb[l0[1]]; w[2] = cb[l0[2]]; w[3] = cb[l0[3]];
    w[4] = cb[l1[0]]; w[5] = cb[l1[1]]; w[6] = cb[l1[2]]; w[7] = cb[l1[3]];
    *(u16x8*)(wb + i) = w;
  }
}

// --------------------------- cast: x fp32 -> bf16 ---------------------------
__global__ __launch_bounds__(256) void cvt_x(const float* __restrict__ x,
                                             ushort* __restrict__ xb, int n) {
  const int stride = gridDim.x * 256 * 8;
  for (int i = ((int)blockIdx.x * 256 + (int)threadIdx.x) * 8; i < n; i += stride) {
    fvec4 a = *(const fvec4*)(x + i);
    fvec4 b = *(const fvec4*)(x + i + 4);
    u16x8 w;
    w[0] = f2bf(a[0]); w[1] = f2bf(a[1]); w[2] = f2bf(a[2]); w[3] = f2bf(a[3]);
    w[4] = f2bf(b[0]); w[5] = f2bf(b[1]); w[6] = f2bf(b[2]); w[7] = f2bf(b[3]);
    *(u16x8*)(xb + i) = w;
  }
}

// --------------------------- 256^2 8-phase bf16 GEMM ------------------------
// C[M][N] = A[M][K] * B[N][K]^T + bias.
// Tile 256x256, BK=64, 512 threads = 8 waves (2M x 4N), wave out = 128x64.
// LDS: per buffer, A and B tiles stored as 2 K-half panels [256][32] bf16
// (16 KB each, contiguous -> global_load_lds-compatible). XOR swizzle
// elem ^= ((row&3)<<3) applied on global source (write side) and ds_read
// (read side). Counted vmcnt(4) at phases 1,3; never 0 in main loop.
__global__ __launch_bounds__(512, 2) void gemm8p(const ushort* __restrict__ A,
                                                 const ushort* __restrict__ B,
                                                 const float* __restrict__ bias,
                                                 float* __restrict__ C) {
  __shared__ ushort As[2][2][8192];   // [buf][khalf][256*32]
  __shared__ ushort Bs[2][2][8192];

  const int tid  = threadIdx.x;
  const int wid  = tid >> 6;
  const int lane = tid & 63;
  const int wm = wid >> 2, wn = wid & 3;
  const int l15 = lane & 15;

  // bijective XCD-aware swizzle (m204)
  const int nwg = gridDim.x, bid = blockIdx.x;
  const int q = nwg >> 3, r = nwg & 7;
  const int xcd = bid & 7, sub = bid >> 3;
  const int swz = (xcd < r ? xcd * (q + 1) : r * (q + 1) + (xcd - r) * q) + sub;
  const int gn = N_DIM / 256;          // 16
  const int bm = swz / gn, bn = swz % gn;

  // ---- staging addressing: half-tile = 16KB = 16 chunks of 1KB; wave owns
  // chunks 2w,2w+1. chunk = 16 rows x 32 elems. lane -> row=lane>>2,
  // elem=(lane&3)*8, source pre-swizzled by ((row&3)<<3).
  const int srow = lane >> 2;
  const int seu  = ((lane & 3) * 8) ^ ((srow & 3) << 3);
  const int chA  = wid * 2;
  const ushort* gAs0 = A + (size_t)(bm * 256 + chA * 16 + srow) * K_DIM + seu;
  const ushort* gAs1 = gAs0 + (size_t)16 * K_DIM;
  const ushort* gBs0 = B + (size_t)(bn * 256 + chA * 16 + srow) * K_DIM + seu;
  const ushort* gBs1 = gBs0 + (size_t)16 * K_DIM;

  // ---- fragment read offsets (swizzled): row = frag_row, elem = (lane>>4)*8
  const int esw  = ((lane >> 4) * 8) ^ ((lane & 3) << 3);
  const int aRow = (wm * 128 + l15) * 32 + esw;
  const int bRow = (wn * 64  + l15) * 32 + esw;

  f32x4 acc[8][4];
#pragma unroll
  for (int i = 0; i < 8; ++i)
#pragma unroll
    for (int j = 0; j < 4; ++j) acc[i][j] = (f32x4){0.f, 0.f, 0.f, 0.f};

  bf16x8 af[4], bfv[4];

#define SA_(b, h, kt)                                              \
  do {                                                             \
    async16(gAs0 + (kt) + (h) * 32, &As[b][h][chA * 512]);         \
    async16(gAs1 + (kt) + (h) * 32, &As[b][h][chA * 512 + 512]);   \
  } while (0)
#define SB_(b, h, kt)                                              \
  do {                                                             \
    async16(gBs0 + (kt) + (h) * 32, &Bs[b][h][chA * 512]);         \
    async16(gBs1 + (kt) + (h) * 32, &Bs[b][h][chA * 512 + 512]);   \
  } while (0)
#define LDA_(b, ks, mh)                                            \
  do {                                                             \
    const ushort* p_ = &As[b][ks][aRow];                           \
    _Pragma("unroll") for (int m_ = 0; m_ < 4; ++m_)               \
        af[m_] = *(const bf16x8*)(p_ + ((mh) * 4 + m_) * 512);     \
  } while (0)
#define LDB_(b, ks)                                                \
  do {                                                             \
    const ushort* p_ = &Bs[b][ks][bRow];                           \
    _Pragma("unroll") for (int n_ = 0; n_ < 4; ++n_)               \
        bfv[n_] = *(const bf16x8*)(p_ + n_ * 512);                 \
  } while (0)
#define MM_(mh)                                                          \
  do {                                                                   \
    __builtin_amdgcn_s_setprio(1);                                       \
    _Pragma("unroll") for (int m_ = 0; m_ < 4; ++m_)                     \
        _Pragma("unroll") for (int n_ = 0; n_ < 4; ++n_)                 \
            acc[(mh) * 4 + m_][n_] =                                     \
            __builtin_amdgcn_mfma_f32_16x16x32_bf16(                     \
                af[m_], bfv[n_], acc[(mh) * 4 + m_][n_], 0, 0, 0);       \
    __builtin_amdgcn_s_setprio(0);                                       \
  } while (0)
#define VMW4 asm volatile("s_waitcnt vmcnt(4)" ::: "memory")
#define BAR  __builtin_amdgcn_s_barrier()

  // prologue: stage tile 0 (order Ak0, Bk0, Ak1, Bk1), wait for k0 halves
  SA_(0, 0, 0); SB_(0, 0, 0); SA_(0, 1, 0); SB_(0, 1, 0);
  VMW4;
  BAR;

  for (int t = 0; t < NT - 1; ++t) {
    const int b = t & 1, nb = b ^ 1;
    const int kn = (t + 1) * 64;
    // phase 0 (ks=0, mh=0) — stage next Ak0
    LDA_(b, 0, 0); LDB_(b, 0);
    SA_(nb, 0, kn);
    BAR; MM_(0); BAR;
    // phase 1 (ks=0, mh=1) — stage next Bk0; wait: this tile's k1 halves done
    LDA_(b, 0, 1);
    SB_(nb, 0, kn);
    VMW4; BAR; MM_(1); BAR;
    // phase 2 (ks=1, mh=0) — stage next Ak1
    LDA_(b, 1, 0); LDB_(b, 1);
    SA_(nb, 1, kn);
    BAR; MM_(0); BAR;
    // phase 3 (ks=1, mh=1) — stage next Bk1; wait: next tile's k0 halves done
    LDA_(b, 1, 1);
    SB_(nb, 1, kn);
    VMW4; BAR; MM_(1); BAR;
  }

  // epilogue tile (t = NT-1, buffer 1, no staging)
  LDA_(1, 0, 0); LDB_(1, 0); MM_(0);
  LDA_(1, 0, 1); MM_(1);
  asm volatile("s_waitcnt vmcnt(0)" ::: "memory");
  BAR;
  LDA_(1, 1, 0); LDB_(1, 1); MM_(0);
  LDA_(1, 1, 1); MM_(1);

#undef SA_
#undef SB_
#undef LDA_
#undef LDB_
#undef MM_
#undef VMW4
#undef BAR

  // C write: C/D layout col = lane&15, row = (lane>>4)*4 + reg
  float bv[4];
#pragma unroll
  for (int n = 0; n < 4; ++n) bv[n] = bias[bn * 256 + wn * 64 + n * 16 + l15];

  float* Cp = C + (size_t)(bm * 256) * N_DIM + bn * 256 + wn * 64;
  const int rbase = (lane >> 4) * 4;
#pragma unroll
  for (int mi = 0; mi < 8; ++mi)
#pragma unroll
    for (int rr = 0; rr < 4; ++rr) {
      float* cr = Cp + (size_t)(wm * 128 + mi * 16 + rbase + rr) * N_DIM;
#pragma unroll
      for (int n = 0; n < 4; ++n)
        cr[n * 16 + l15] = acc[mi][n][rr] + bv[n];
    }
}

// --------------------------- naive fallback (ws too small) ------------------
__global__ void naive_kernel(const float* __restrict__ x,
                             const float* __restrict__ cent,
                             const int* __restrict__ labels,
                             const float* __restrict__ bias,
                             float* __restrict__ out, int M) {
  __shared__ float cb[256];
  if (threadIdx.x < 256) cb[threadIdx.x] = cent[threadIdx.x];
  __syncthreads();
  long o = (long)blockIdx.x * blockDim.x + threadIdx.x;
  if (o >= (long)M * N_DIM) return;
  int n = (int)(o % N_DIM);
  long m = o / N_DIM;
  const float* xr = x + m * K_DIM;
  const int* lr = labels + (long)n * K_DIM;
  float s = 0.f;
  for (int k = 0; k < K_DIM; ++k) s += xr[k] * cb[lr[k]];
  out[o] = s + bias[n];
}

// ---------------------------------------------------------------------------
extern "C" void kernel_launch(void* const* d_in, const int* in_sizes, int n_in,
                              void* d_out, int out_size, void* d_ws, size_t ws_size,
                              hipStream_t stream) {
  const float* x      = (const float*)d_in[0];
  const float* cent   = (const float*)d_in[1];
  const int*   labels = (const int*)d_in[2];
  const float* bias   = (const float*)d_in[3];
  float* out = (float*)d_out;

  const int xN = in_sizes[0];      // M*K
  const int M  = xN / K_DIM;       // 8192
  const int wN = in_sizes[2];      // N*K

  const size_t need = (size_t)wN * 2 + (size_t)xN * 2;  // 96 MB
  if (ws_size < need || (M % 256) != 0) {
    long total = (long)M * N_DIM;
    int blocks = (int)((total + 255) / 256);
    naive_kernel<<<blocks, 256, 0, stream>>>(x, cent, labels, bias, out, M);
    return;
  }

  ushort* wb = (ushort*)d_ws;      // [N][K] bf16
  ushort* xb = wb + (size_t)wN;    // [M][K] bf16

  dequant_w<<<2048, 256, 0, stream>>>(labels, cent, wb, wN);
  cvt_x<<<2048, 256, 0, stream>>>(x, xb, xN);

  const int grid = (M / 256) * (N_DIM / 256);  // 512
  gemm8p<<<grid, 512, 0, stream>>>(xb, wb, bias, out);
}

// Round 3
// 338.402 us; speedup vs baseline: 1.1349x; 1.0404x over previous
//
#include <hip/hip_runtime.h>
#include <stdint.h>

// ---------------------------------------------------------------------------
// FlatLinear: y = x @ W^T + bias, W = centroids[labels] (4096x4096, K=256 cb)
// M=8192, N=4096, K=4096.  dequant W->bf16, cast x->bf16, then 256x256-tile
// 8-phase bf16 MFMA GEMM (BK=64, 8 waves, counted vmcnt, XOR-swizzled LDS).
// R3: fixed read swizzle to unit ^= ((row>>1)&3) -> 2 lanes/bank-quad per
// 16-lane subgroup (conflict-free floor); prev (row&3) gave 4-way conflicts.
// ---------------------------------------------------------------------------

typedef __attribute__((ext_vector_type(8))) short  bf16x8;
typedef __attribute__((ext_vector_type(4))) float  f32x4;
typedef __attribute__((ext_vector_type(4))) int    i32x4;
typedef __attribute__((ext_vector_type(8))) ushort u16x8;
typedef __attribute__((ext_vector_type(4))) float  fvec4;

#define K_DIM 4096
#define N_DIM 4096
#define NT    (K_DIM / 64)   // 64 K-tiles of BK=64

__device__ __forceinline__ ushort f2bf(float f) {
  uint32_t u = __float_as_uint(f);
  return (ushort)((u + 0x7fffu + ((u >> 16) & 1u)) >> 16);
}

__device__ __forceinline__ void async16(const ushort* g, ushort* l) {
  __builtin_amdgcn_global_load_lds(
      (const __attribute__((address_space(1))) void*)g,
      (__attribute__((address_space(3))) void*)l, 16, 0, 0);
}

// --------------------------- dequant: labels -> bf16 W ---------------------
__global__ __launch_bounds__(256) void dequant_w(const int* __restrict__ labels,
                                                 const float* __restrict__ cent,
                                                 ushort* __restrict__ wb, int n) {
  __shared__ ushort cb[256];
  cb[threadIdx.x] = f2bf(cent[threadIdx.x]);
  __syncthreads();
  const int stride = gridDim.x * 256 * 8;
  for (int i = ((int)blockIdx.x * 256 + (int)threadIdx.x) * 8; i < n; i += stride) {
    i32x4 l0 = *(const i32x4*)(labels + i);
    i32x4 l1 = *(const i32x4*)(labels + i + 4);
    u16x8 w;
    w[0] = cb[l0[0]]; w[1] = cb[l0[1]]; w[2] = cb[l0[2]]; w[3] = cb[l0[3]];
    w[4] = cb[l1[0]]; w[5] = cb[l1[1]]; w[6] = cb[l1[2]]; w[7] = cb[l1[3]];
    *(u16x8*)(wb + i) = w;
  }
}

// --------------------------- cast: x fp32 -> bf16 ---------------------------
__global__ __launch_bounds__(256) void cvt_x(const float* __restrict__ x,
                                             ushort* __restrict__ xb, int n) {
  const int stride = gridDim.x * 256 * 8;
  for (int i = ((int)blockIdx.x * 256 + (int)threadIdx.x) * 8; i < n; i += stride) {
    fvec4 a = *(const fvec4*)(x + i);
    fvec4 b = *(const fvec4*)(x + i + 4);
    u16x8 w;
    w[0] = f2bf(a[0]); w[1] = f2bf(a[1]); w[2] = f2bf(a[2]); w[3] = f2bf(a[3]);
    w[4] = f2bf(b[0]); w[5] = f2bf(b[1]); w[6] = f2bf(b[2]); w[7] = f2bf(b[3]);
    *(u16x8*)(xb + i) = w;
  }
}

// --------------------------- 256^2 8-phase bf16 GEMM ------------------------
// C[M][N] = A[M][K] * B[N][K]^T + bias.
// Tile 256x256, BK=64, 512 threads = 8 waves (2M x 4N), wave out = 128x64.
// LDS: per buffer, A and B tiles stored as 2 K-half panels [256][32] bf16
// (16 KB each, contiguous -> global_load_lds-compatible). XOR swizzle
// 16B-unit ^= ((row>>1)&3) applied on global source (write side) and ds_read
// (read side). Counted vmcnt(4) at phases 1,3; never 0 in main loop.
__global__ __launch_bounds__(512, 2) void gemm8p(const ushort* __restrict__ A,
                                                 const ushort* __restrict__ B,
                                                 const float* __restrict__ bias,
                                                 float* __restrict__ C) {
  __shared__ ushort As[2][2][8192];   // [buf][khalf][256*32]
  __shared__ ushort Bs[2][2][8192];

  const int tid  = threadIdx.x;
  const int wid  = tid >> 6;
  const int lane = tid & 63;
  const int wm = wid >> 2, wn = wid & 3;
  const int l15 = lane & 15;

  // bijective XCD-aware swizzle (m204)
  const int nwg = gridDim.x, bid = blockIdx.x;
  const int q = nwg >> 3, r = nwg & 7;
  const int xcd = bid & 7, sub = bid >> 3;
  const int swz = (xcd < r ? xcd * (q + 1) : r * (q + 1) + (xcd - r) * q) + sub;
  const int gn = N_DIM / 256;          // 16
  const int bm = swz / gn, bn = swz % gn;

  // ---- staging addressing: half-tile = 16KB = 16 chunks of 1KB; wave owns
  // chunks 2w,2w+1. chunk = 16 rows x 32 elems. lane -> row=lane>>2,
  // elem=(lane&3)*8, source pre-swizzled: unit ^= ((row>>1)&3).
  const int srow = lane >> 2;
  const int seu  = ((lane & 3) * 8) ^ (((srow >> 1) & 3) << 3);
  const int chA  = wid * 2;
  const ushort* gAs0 = A + (size_t)(bm * 256 + chA * 16 + srow) * K_DIM + seu;
  const ushort* gAs1 = gAs0 + (size_t)16 * K_DIM;
  const ushort* gBs0 = B + (size_t)(bn * 256 + chA * 16 + srow) * K_DIM + seu;
  const ushort* gBs1 = gBs0 + (size_t)16 * K_DIM;

  // ---- fragment read offsets (swizzled): row = frag + l15,
  // unit = (lane>>4) ^ ((row>>1)&3) = (lane>>4) ^ ((l15>>1)&3)
  const int esw  = ((lane >> 4) * 8) ^ (((l15 >> 1) & 3) << 3);
  const int aRow = (wm * 128 + l15) * 32 + esw;
  const int bRow = (wn * 64  + l15) * 32 + esw;

  f32x4 acc[8][4];
#pragma unroll
  for (int i = 0; i < 8; ++i)
#pragma unroll
    for (int j = 0; j < 4; ++j) acc[i][j] = (f32x4){0.f, 0.f, 0.f, 0.f};

  bf16x8 af[4], bfv[4];

#define SA_(b, h, kt)                                              \
  do {                                                             \
    async16(gAs0 + (kt) + (h) * 32, &As[b][h][chA * 512]);         \
    async16(gAs1 + (kt) + (h) * 32, &As[b][h][chA * 512 + 512]);   \
  } while (0)
#define SB_(b, h, kt)                                              \
  do {                                                             \
    async16(gBs0 + (kt) + (h) * 32, &Bs[b][h][chA * 512]);         \
    async16(gBs1 + (kt) + (h) * 32, &Bs[b][h][chA * 512 + 512]);   \
  } while (0)
#define LDA_(b, ks, mh)                                            \
  do {                                                             \
    const ushort* p_ = &As[b][ks][aRow];                           \
    _Pragma("unroll") for (int m_ = 0; m_ < 4; ++m_)               \
        af[m_] = *(const bf16x8*)(p_ + ((mh) * 4 + m_) * 512);     \
  } while (0)
#define LDB_(b, ks)                                                \
  do {                                                             \
    const ushort* p_ = &Bs[b][ks][bRow];                           \
    _Pragma("unroll") for (int n_ = 0; n_ < 4; ++n_)               \
        bfv[n_] = *(const bf16x8*)(p_ + n_ * 512);                 \
  } while (0)
#define MM_(mh)                                                          \
  do {                                                                   \
    __builtin_amdgcn_s_setprio(1);                                       \
    _Pragma("unroll") for (int m_ = 0; m_ < 4; ++m_)                     \
        _Pragma("unroll") for (int n_ = 0; n_ < 4; ++n_)                 \
            acc[(mh) * 4 + m_][n_] =                                     \
            __builtin_amdgcn_mfma_f32_16x16x32_bf16(                     \
                af[m_], bfv[n_], acc[(mh) * 4 + m_][n_], 0, 0, 0);       \
    __builtin_amdgcn_s_setprio(0);                                       \
  } while (0)
#define VMW4 asm volatile("s_waitcnt vmcnt(4)" ::: "memory")
#define BAR  __builtin_amdgcn_s_barrier()

  // prologue: stage tile 0 (order Ak0, Bk0, Ak1, Bk1), wait for k0 halves
  SA_(0, 0, 0); SB_(0, 0, 0); SA_(0, 1, 0); SB_(0, 1, 0);
  VMW4;
  BAR;

  for (int t = 0; t < NT - 1; ++t) {
    const int b = t & 1, nb = b ^ 1;
    const int kn = (t + 1) * 64;
    // phase 0 (ks=0, mh=0) — stage next Ak0
    LDA_(b, 0, 0); LDB_(b, 0);
    SA_(nb, 0, kn);
    BAR; MM_(0); BAR;
    // phase 1 (ks=0, mh=1) — stage next Bk0; wait: this tile's k1 halves done
    LDA_(b, 0, 1);
    SB_(nb, 0, kn);
    VMW4; BAR; MM_(1); BAR;
    // phase 2 (ks=1, mh=0) — stage next Ak1
    LDA_(b, 1, 0); LDB_(b, 1);
    SA_(nb, 1, kn);
    BAR; MM_(0); BAR;
    // phase 3 (ks=1, mh=1) — stage next Bk1; wait: next tile's k0 halves done
    LDA_(b, 1, 1);
    SB_(nb, 1, kn);
    VMW4; BAR; MM_(1); BAR;
  }

  // epilogue tile (t = NT-1, buffer 1, no staging)
  LDA_(1, 0, 0); LDB_(1, 0); MM_(0);
  LDA_(1, 0, 1); MM_(1);
  asm volatile("s_waitcnt vmcnt(0)" ::: "memory");
  BAR;
  LDA_(1, 1, 0); LDB_(1, 1); MM_(0);
  LDA_(1, 1, 1); MM_(1);

#undef SA_
#undef SB_
#undef LDA_
#undef LDB_
#undef MM_
#undef VMW4
#undef BAR

  // C write: C/D layout col = lane&15, row = (lane>>4)*4 + reg
  float bv[4];
#pragma unroll
  for (int n = 0; n < 4; ++n) bv[n] = bias[bn * 256 + wn * 64 + n * 16 + l15];

  float* Cp = C + (size_t)(bm * 256) * N_DIM + bn * 256 + wn * 64;
  const int rbase = (lane >> 4) * 4;
#pragma unroll
  for (int mi = 0; mi < 8; ++mi)
#pragma unroll
    for (int rr = 0; rr < 4; ++rr) {
      float* cr = Cp + (size_t)(wm * 128 + mi * 16 + rbase + rr) * N_DIM;
#pragma unroll
      for (int n = 0; n < 4; ++n)
        cr[n * 16 + l15] = acc[mi][n][rr] + bv[n];
    }
}

// --------------------------- naive fallback (ws too small) ------------------
__global__ void naive_kernel(const float* __restrict__ x,
                             const float* __restrict__ cent,
                             const int* __restrict__ labels,
                             const float* __restrict__ bias,
                             float* __restrict__ out, int M) {
  __shared__ float cb[256];
  if (threadIdx.x < 256) cb[threadIdx.x] = cent[threadIdx.x];
  __syncthreads();
  long o = (long)blockIdx.x * blockDim.x + threadIdx.x;
  if (o >= (long)M * N_DIM) return;
  int n = (int)(o % N_DIM);
  long m = o / N_DIM;
  const float* xr = x + m * K_DIM;
  const int* lr = labels + (long)n * K_DIM;
  float s = 0.f;
  for (int k = 0; k < K_DIM; ++k) s += xr[k] * cb[lr[k]];
  out[o] = s + bias[n];
}

// ---------------------------------------------------------------------------
extern "C" void kernel_launch(void* const* d_in, const int* in_sizes, int n_in,
                              void* d_out, int out_size, void* d_ws, size_t ws_size,
                              hipStream_t stream) {
  const float* x      = (const float*)d_in[0];
  const float* cent   = (const float*)d_in[1];
  const int*   labels = (const int*)d_in[2];
  const float* bias   = (const float*)d_in[3];
  float* out = (float*)d_out;

  const int xN = in_sizes[0];      // M*K
  const int M  = xN / K_DIM;       // 8192
  const int wN = in_sizes[2];      // N*K

  const size_t need = (size_t)wN * 2 + (size_t)xN * 2;  // 96 MB
  if (ws_size < need || (M % 256) != 0) {
    long total = (long)M * N_DIM;
    int blocks = (int)((total + 255) / 256);
    naive_kernel<<<blocks, 256, 0, stream>>>(x, cent, labels, bias, out, M);
    return;
  }

  ushort* wb = (ushort*)d_ws;      // [N][K] bf16
  ushort* xb = wb + (size_t)wN;    // [M][K] bf16

  dequant_w<<<2048, 256, 0, stream>>>(labels, cent, wb, wN);
  cvt_x<<<2048, 256, 0, stream>>>(x, xb, xN);

  const int grid = (M / 256) * (N_DIM / 256);  // 512
  gemm8p<<<grid, 512, 0, stream>>>(xb, wb, bias, out);
}

// Round 4
// 324.966 us; speedup vs baseline: 1.1818x; 1.0413x over previous
//
#include <hip/hip_runtime.h>
#include <stdint.h>

// ---------------------------------------------------------------------------
// FlatLinear: y = x @ W^T + bias, W = centroids[labels] (4096x4096, K=256 cb)
// M=8192, N=4096, K=4096.  dequant W->bf16, cast x->bf16, then 256x256-tile
// 8-phase bf16 MFMA GEMM (BK=64, 8 waves, counted vmcnt, XOR-swizzled LDS).
// R4: fragment ds_reads software-pipelined ONE PHASE AHEAD into double-
// buffered register sets (afA/afB by phase parity, bvA/bvB by k-slice) so
// LDS reads overlap the previous phase's MFMA block instead of serializing.
// ---------------------------------------------------------------------------

typedef __attribute__((ext_vector_type(8))) short  bf16x8;
typedef __attribute__((ext_vector_type(4))) float  f32x4;
typedef __attribute__((ext_vector_type(4))) int    i32x4;
typedef __attribute__((ext_vector_type(8))) ushort u16x8;
typedef __attribute__((ext_vector_type(4))) float  fvec4;

#define K_DIM 4096
#define N_DIM 4096
#define NT    (K_DIM / 64)   // 64 K-tiles of BK=64

__device__ __forceinline__ ushort f2bf(float f) {
  uint32_t u = __float_as_uint(f);
  return (ushort)((u + 0x7fffu + ((u >> 16) & 1u)) >> 16);
}

__device__ __forceinline__ void async16(const ushort* g, ushort* l) {
  __builtin_amdgcn_global_load_lds(
      (const __attribute__((address_space(1))) void*)g,
      (__attribute__((address_space(3))) void*)l, 16, 0, 0);
}

// --------------------------- dequant: labels -> bf16 W ---------------------
__global__ __launch_bounds__(256) void dequant_w(const int* __restrict__ labels,
                                                 const float* __restrict__ cent,
                                                 ushort* __restrict__ wb, int n) {
  __shared__ ushort cb[256];
  cb[threadIdx.x] = f2bf(cent[threadIdx.x]);
  __syncthreads();
  const int stride = gridDim.x * 256 * 8;
  for (int i = ((int)blockIdx.x * 256 + (int)threadIdx.x) * 8; i < n; i += stride) {
    i32x4 l0 = *(const i32x4*)(labels + i);
    i32x4 l1 = *(const i32x4*)(labels + i + 4);
    u16x8 w;
    w[0] = cb[l0[0]]; w[1] = cb[l0[1]]; w[2] = cb[l0[2]]; w[3] = cb[l0[3]];
    w[4] = cb[l1[0]]; w[5] = cb[l1[1]]; w[6] = cb[l1[2]]; w[7] = cb[l1[3]];
    *(u16x8*)(wb + i) = w;
  }
}

// --------------------------- cast: x fp32 -> bf16 ---------------------------
__global__ __launch_bounds__(256) void cvt_x(const float* __restrict__ x,
                                             ushort* __restrict__ xb, int n) {
  const int stride = gridDim.x * 256 * 8;
  for (int i = ((int)blockIdx.x * 256 + (int)threadIdx.x) * 8; i < n; i += stride) {
    fvec4 a = *(const fvec4*)(x + i);
    fvec4 b = *(const fvec4*)(x + i + 4);
    u16x8 w;
    w[0] = f2bf(a[0]); w[1] = f2bf(a[1]); w[2] = f2bf(a[2]); w[3] = f2bf(a[3]);
    w[4] = f2bf(b[0]); w[5] = f2bf(b[1]); w[6] = f2bf(b[2]); w[7] = f2bf(b[3]);
    *(u16x8*)(xb + i) = w;
  }
}

// --------------------------- 256^2 8-phase bf16 GEMM ------------------------
// C[M][N] = A[M][K] * B[N][K]^T + bias.
// Tile 256x256, BK=64, 512 threads = 8 waves (2M x 4N), wave out = 128x64.
// LDS: per buffer, A and B tiles as 2 K-half panels [256][32] bf16 (16 KB,
// contiguous -> global_load_lds-compatible). XOR swizzle 16B-unit ^=
// ((row>>1)&3) on global source (write side) and ds_read (read side).
// Counted vmcnt(4) at phases 1,3; frag loads prefetched one phase ahead.
__global__ __launch_bounds__(512, 2) void gemm8p(const ushort* __restrict__ A,
                                                 const ushort* __restrict__ B,
                                                 const float* __restrict__ bias,
                                                 float* __restrict__ C) {
  __shared__ ushort As[2][2][8192];   // [buf][khalf][256*32]
  __shared__ ushort Bs[2][2][8192];

  const int tid  = threadIdx.x;
  const int wid  = tid >> 6;
  const int lane = tid & 63;
  const int wm = wid >> 2, wn = wid & 3;
  const int l15 = lane & 15;

  // bijective XCD-aware swizzle (m204)
  const int nwg = gridDim.x, bid = blockIdx.x;
  const int q = nwg >> 3, r = nwg & 7;
  const int xcd = bid & 7, sub = bid >> 3;
  const int swz = (xcd < r ? xcd * (q + 1) : r * (q + 1) + (xcd - r) * q) + sub;
  const int gn = N_DIM / 256;          // 16
  const int bm = swz / gn, bn = swz % gn;

  // ---- staging addressing: half-tile = 16KB = 16 chunks of 1KB; wave owns
  // chunks 2w,2w+1. chunk = 16 rows x 32 elems. lane -> row=lane>>2,
  // elem=(lane&3)*8, source pre-swizzled: unit ^= ((row>>1)&3).
  const int srow = lane >> 2;
  const int seu  = ((lane & 3) * 8) ^ (((srow >> 1) & 3) << 3);
  const int chA  = wid * 2;
  const ushort* gAs0 = A + (size_t)(bm * 256 + chA * 16 + srow) * K_DIM + seu;
  const ushort* gAs1 = gAs0 + (size_t)16 * K_DIM;
  const ushort* gBs0 = B + (size_t)(bn * 256 + chA * 16 + srow) * K_DIM + seu;
  const ushort* gBs1 = gBs0 + (size_t)16 * K_DIM;

  // ---- fragment read offsets (swizzled): row = frag + l15,
  // unit = (lane>>4) ^ ((row>>1)&3) = (lane>>4) ^ ((l15>>1)&3)
  const int esw  = ((lane >> 4) * 8) ^ (((l15 >> 1) & 3) << 3);
  const int aRow = (wm * 128 + l15) * 32 + esw;
  const int bRow = (wn * 64  + l15) * 32 + esw;

  f32x4 acc[8][4];
#pragma unroll
  for (int i = 0; i < 8; ++i)
#pragma unroll
    for (int j = 0; j < 4; ++j) acc[i][j] = (f32x4){0.f, 0.f, 0.f, 0.f};

  bf16x8 afA[4], afB[4], bvA[4], bvB[4];

#define SA_(b, h, kt)                                              \
  do {                                                             \
    async16(gAs0 + (kt) + (h) * 32, &As[b][h][chA * 512]);         \
    async16(gAs1 + (kt) + (h) * 32, &As[b][h][chA * 512 + 512]);   \
  } while (0)
#define SB_(b, h, kt)                                              \
  do {                                                             \
    async16(gBs0 + (kt) + (h) * 32, &Bs[b][h][chA * 512]);         \
    async16(gBs1 + (kt) + (h) * 32, &Bs[b][h][chA * 512 + 512]);   \
  } while (0)
#define LDA_(dst, b, ks, mh)                                       \
  do {                                                             \
    const ushort* p_ = &As[b][ks][aRow];                           \
    _Pragma("unroll") for (int m_ = 0; m_ < 4; ++m_)               \
        dst[m_] = *(const bf16x8*)(p_ + ((mh) * 4 + m_) * 512);    \
  } while (0)
#define LDB_(dst, b, ks)                                           \
  do {                                                             \
    const ushort* p_ = &Bs[b][ks][bRow];                           \
    _Pragma("unroll") for (int n_ = 0; n_ < 4; ++n_)               \
        dst[n_] = *(const bf16x8*)(p_ + n_ * 512);                 \
  } while (0)
#define MM_(a_, b_, mh)                                                  \
  do {                                                                   \
    __builtin_amdgcn_s_setprio(1);                                       \
    _Pragma("unroll") for (int m_ = 0; m_ < 4; ++m_)                     \
        _Pragma("unroll") for (int n_ = 0; n_ < 4; ++n_)                 \
            acc[(mh) * 4 + m_][n_] =                                     \
            __builtin_amdgcn_mfma_f32_16x16x32_bf16(                     \
                a_[m_], b_[n_], acc[(mh) * 4 + m_][n_], 0, 0, 0);        \
    __builtin_amdgcn_s_setprio(0);                                       \
  } while (0)
#define VMW4 asm volatile("s_waitcnt vmcnt(4)" ::: "memory")
#define BAR  __builtin_amdgcn_s_barrier()

  // prologue: stage tile 0 (Ak0, Bk0, Ak1, Bk1), wait k0 halves, preload
  // phase-0 fragments.
  SA_(0, 0, 0); SB_(0, 0, 0); SA_(0, 1, 0); SB_(0, 1, 0);
  VMW4;
  BAR;
  LDA_(afA, 0, 0, 0); LDB_(bvA, 0, 0);

  for (int t = 0; t < NT - 1; ++t) {
    const int b = t & 1, nb = b ^ 1;
    const int kn = (t + 1) * 64;
    // P0: prefetch frags for P1 (b,ks0,mh1); stage next A-k0
    LDA_(afB, b, 0, 1);
    SA_(nb, 0, kn);
    BAR; MM_(afA, bvA, 0); BAR;
    // P1: stage next B-k0; wait this tile's k1; prefetch P2 frags (b,ks1)
    //     overlapping this phase's MFMA block
    SB_(nb, 0, kn);
    VMW4; BAR;
    LDA_(afA, b, 1, 0); LDB_(bvB, b, 1);
    MM_(afB, bvA, 1); BAR;
    // P2: prefetch P3 frags (b,ks1,mh1); stage next A-k1
    LDA_(afB, b, 1, 1);
    SA_(nb, 1, kn);
    BAR; MM_(afA, bvB, 0); BAR;
    // P3: stage next B-k1; wait next tile's k0; prefetch next-P0 frags
    SB_(nb, 1, kn);
    VMW4; BAR;
    LDA_(afA, nb, 0, 0); LDB_(bvA, nb, 0);
    MM_(afB, bvB, 1); BAR;
  }

  // epilogue tile (t = NT-1, buffer 1, no staging; afA/bvA preloaded)
  LDA_(afB, 1, 0, 1);
  MM_(afA, bvA, 0);
  asm volatile("s_waitcnt vmcnt(0)" ::: "memory");
  BAR;
  LDA_(afA, 1, 1, 0); LDB_(bvB, 1, 1);
  MM_(afB, bvA, 1);
  LDA_(afB, 1, 1, 1);
  MM_(afA, bvB, 0);
  MM_(afB, bvB, 1);

#undef SA_
#undef SB_
#undef LDA_
#undef LDB_
#undef MM_
#undef VMW4
#undef BAR

  // C write: C/D layout col = lane&15, row = (lane>>4)*4 + reg
  float bv[4];
#pragma unroll
  for (int n = 0; n < 4; ++n) bv[n] = bias[bn * 256 + wn * 64 + n * 16 + l15];

  float* Cp = C + (size_t)(bm * 256) * N_DIM + bn * 256 + wn * 64;
  const int rbase = (lane >> 4) * 4;
#pragma unroll
  for (int mi = 0; mi < 8; ++mi)
#pragma unroll
    for (int rr = 0; rr < 4; ++rr) {
      float* cr = Cp + (size_t)(wm * 128 + mi * 16 + rbase + rr) * N_DIM;
#pragma unroll
      for (int n = 0; n < 4; ++n)
        cr[n * 16 + l15] = acc[mi][n][rr] + bv[n];
    }
}

// --------------------------- naive fallback (ws too small) ------------------
__global__ void naive_kernel(const float* __restrict__ x,
                             const float* __restrict__ cent,
                             const int* __restrict__ labels,
                             const float* __restrict__ bias,
                             float* __restrict__ out, int M) {
  __shared__ float cb[256];
  if (threadIdx.x < 256) cb[threadIdx.x] = cent[threadIdx.x];
  __syncthreads();
  long o = (long)blockIdx.x * blockDim.x + threadIdx.x;
  if (o >= (long)M * N_DIM) return;
  int n = (int)(o % N_DIM);
  long m = o / N_DIM;
  const float* xr = x + m * K_DIM;
  const int* lr = labels + (long)n * K_DIM;
  float s = 0.f;
  for (int k = 0; k < K_DIM; ++k) s += xr[k] * cb[lr[k]];
  out[o] = s + bias[n];
}

// ---------------------------------------------------------------------------
extern "C" void kernel_launch(void* const* d_in, const int* in_sizes, int n_in,
                              void* d_out, int out_size, void* d_ws, size_t ws_size,
                              hipStream_t stream) {
  const float* x      = (const float*)d_in[0];
  const float* cent   = (const float*)d_in[1];
  const int*   labels = (const int*)d_in[2];
  const float* bias   = (const float*)d_in[3];
  float* out = (float*)d_out;

  const int xN = in_sizes[0];      // M*K
  const int M  = xN / K_DIM;       // 8192
  const int wN = in_sizes[2];      // N*K

  const size_t need = (size_t)wN * 2 + (size_t)xN * 2;  // 96 MB
  if (ws_size < need || (M % 256) != 0) {
    long total = (long)M * N_DIM;
    int blocks = (int)((total + 255) / 256);
    naive_kernel<<<blocks, 256, 0, stream>>>(x, cent, labels, bias, out, M);
    return;
  }

  ushort* wb = (ushort*)d_ws;      // [N][K] bf16
  ushort* xb = wb + (size_t)wN;    // [M][K] bf16

  dequant_w<<<2048, 256, 0, stream>>>(labels, cent, wb, wN);
  cvt_x<<<2048, 256, 0, stream>>>(x, xb, xN);

  const int grid = (M / 256) * (N_DIM / 256);  // 512
  gemm8p<<<grid, 512, 0, stream>>>(xb, wb, bias, out);
}

// Round 6
// 319.938 us; speedup vs baseline: 1.2004x; 1.0157x over previous
//
#include <hip/hip_runtime.h>
#include <stdint.h>

// ---------------------------------------------------------------------------
// FlatLinear: y = x @ W^T + bias, W = centroids[labels] (4096x4096, K=256 cb)
// M=8192, N=4096, K=4096.  dequant W->bf16, cast x->bf16, then MFMA GEMM.
// R6: R5 design (256x128 tile, BK=32, 8 waves 4x2, LDS 48 KiB, 2 blocks/CU)
// with the staging bug fixed: A upper-half LDS dest is +4096 ushorts (row
// 128), not +8192 (was overflowing the panel -> NaN). LDS dests now
// explicitly wave-uniform; K-loop unrolled x2 so buffer index is static.
// ---------------------------------------------------------------------------

typedef __attribute__((ext_vector_type(8))) short  bf16x8;
typedef __attribute__((ext_vector_type(4))) float  f32x4;
typedef __attribute__((ext_vector_type(4))) int    i32x4;
typedef __attribute__((ext_vector_type(8))) ushort u16x8;
typedef __attribute__((ext_vector_type(4))) float  fvec4;

#define K_DIM 4096
#define N_DIM 4096
#define NSTEP (K_DIM / 32)   // 128 K-steps of BK=32

__device__ __forceinline__ ushort f2bf(float f) {
  uint32_t u = __float_as_uint(f);
  return (ushort)((u + 0x7fffu + ((u >> 16) & 1u)) >> 16);
}

__device__ __forceinline__ void async16(const ushort* g, ushort* l) {
  __builtin_amdgcn_global_load_lds(
      (const __attribute__((address_space(1))) void*)g,
      (__attribute__((address_space(3))) void*)l, 16, 0, 0);
}

// --------------------------- dequant: labels -> bf16 W ---------------------
__global__ __launch_bounds__(256) void dequant_w(const int* __restrict__ labels,
                                                 const float* __restrict__ cent,
                                                 ushort* __restrict__ wb, int n) {
  __shared__ ushort cb[256];
  cb[threadIdx.x] = f2bf(cent[threadIdx.x]);
  __syncthreads();
  const int stride = gridDim.x * 256 * 8;
  for (int i = ((int)blockIdx.x * 256 + (int)threadIdx.x) * 8; i < n; i += stride) {
    i32x4 l0 = *(const i32x4*)(labels + i);
    i32x4 l1 = *(const i32x4*)(labels + i + 4);
    u16x8 w;
    w[0] = cb[l0[0]]; w[1] = cb[l0[1]]; w[2] = cb[l0[2]]; w[3] = cb[l0[3]];
    w[4] = cb[l1[0]]; w[5] = cb[l1[1]]; w[6] = cb[l1[2]]; w[7] = cb[l1[3]];
    *(u16x8*)(wb + i) = w;
  }
}

// --------------------------- cast: x fp32 -> bf16 ---------------------------
__global__ __launch_bounds__(256) void cvt_x(const float* __restrict__ x,
                                             ushort* __restrict__ xb, int n) {
  const int stride = gridDim.x * 256 * 8;
  for (int i = ((int)blockIdx.x * 256 + (int)threadIdx.x) * 8; i < n; i += stride) {
    fvec4 a = *(const fvec4*)(x + i);
    fvec4 b = *(const fvec4*)(x + i + 4);
    u16x8 w;
    w[0] = f2bf(a[0]); w[1] = f2bf(a[1]); w[2] = f2bf(a[2]); w[3] = f2bf(a[3]);
    w[4] = f2bf(b[0]); w[5] = f2bf(b[1]); w[6] = f2bf(b[2]); w[7] = f2bf(b[3]);
    *(u16x8*)(xb + i) = w;
  }
}

// --------------------------- 256x128-tile bf16 GEMM -------------------------
// C[M][N] = A[M][K] * B[N][K]^T + bias.
// Tile 256x128, BK=32, 512 threads = 8 waves (4M x 2N), wave out = 64x64.
// LDS per buffer: A [256][32] (8192 ushort) + B [128][32] (4096 ushort).
// Staging: 3 async16/thread/step; wave-uniform LDS dest (HW adds lane*16B);
// source pre-swizzled unit ^= ((row>>1)&3); reads use the same XOR
// (conflict-free, verified R3). Per step: frags(buf b), 16 MFMA, vmcnt(0),
// s_barrier. Cross-block desync (2 blocks/CU) hides the drain.
__global__ __launch_bounds__(512, 4) void gemm2(const ushort* __restrict__ A,
                                                const ushort* __restrict__ B,
                                                const float* __restrict__ bias,
                                                float* __restrict__ C) {
  __shared__ ushort As[2][8192];   // [buf][256 rows x 32]
  __shared__ ushort Bs[2][4096];   // [buf][128 rows x 32]

  const int tid  = threadIdx.x;
  const int wid  = tid >> 6;
  const int lane = tid & 63;
  const int wm = wid >> 1, wn = wid & 1;
  const int l15 = lane & 15;

  // bijective XCD-aware swizzle (m204)
  const int nwg = gridDim.x, bid = blockIdx.x;
  const int q = nwg >> 3, r = nwg & 7;
  const int xcd = bid & 7, sub = bid >> 3;
  const int swz = (xcd < r ? xcd * (q + 1) : r * (q + 1) + (xcd - r) * q) + sub;
  const int gn = N_DIM / 128;          // 32
  const int bm = swz / gn, bn = swz % gn;

  // ---- staging: thread tid loads unit tid of A-low (rows 0..127), unit tid
  // of A-high (rows 128..255, LDS elem 4096+), unit tid of B (rows 0..127).
  // unit = 8 ushorts; row = tid>>2; src elem pre-swizzled by ((row>>1)&3)<<3
  // (row+128 keeps the same swizzle: 128>>1 = 64 == 0 mod 4).
  const int srow = tid >> 2;
  const int seu  = ((tid & 3) * 8) ^ (((srow >> 1) & 3) << 3);
  const ushort* gA0 = A + (size_t)(bm * 256 + srow) * K_DIM + seu;
  const ushort* gA1 = gA0 + (size_t)128 * K_DIM;
  const ushort* gB  = B + (size_t)(bn * 128 + srow) * K_DIM + seu;
  const int wbase = wid * 512;  // wave-uniform LDS unit base (64 lanes x 8)

  // ---- fragment read offsets (read-side XOR matches store swizzle):
  //   unit = (lane>>4) ^ ((row>>1)&3), row = <mult of 16> + l15
  const int esw  = ((lane >> 4) * 8) ^ (((l15 >> 1) & 3) << 3);
  const int aOff = (wm * 64 + l15) * 32 + esw;
  const int bOff = (wn * 64 + l15) * 32 + esw;

  f32x4 acc[4][4];
#pragma unroll
  for (int i = 0; i < 4; ++i)
#pragma unroll
    for (int j = 0; j < 4; ++j) acc[i][j] = (f32x4){0.f, 0.f, 0.f, 0.f};

  bf16x8 af[4], bfr[4];

#define STAGE_(b, kt)                               \
  do {                                              \
    async16(gA0 + (kt), &As[b][wbase]);             \
    async16(gA1 + (kt), &As[b][4096 + wbase]);      \
    async16(gB + (kt), &Bs[b][wbase]);              \
  } while (0)
#define LDFRAG_(b)                                                   \
  do {                                                               \
    _Pragma("unroll") for (int m_ = 0; m_ < 4; ++m_)                 \
        af[m_] = *(const bf16x8*)&As[b][aOff + m_ * 512];            \
    _Pragma("unroll") for (int n_ = 0; n_ < 4; ++n_)                 \
        bfr[n_] = *(const bf16x8*)&Bs[b][bOff + n_ * 512];           \
  } while (0)
#define MM_()                                                        \
  do {                                                               \
    __builtin_amdgcn_s_setprio(1);                                   \
    _Pragma("unroll") for (int m_ = 0; m_ < 4; ++m_)                 \
        _Pragma("unroll") for (int n_ = 0; n_ < 4; ++n_)             \
            acc[m_][n_] = __builtin_amdgcn_mfma_f32_16x16x32_bf16(   \
                af[m_], bfr[n_], acc[m_][n_], 0, 0, 0);              \
    __builtin_amdgcn_s_setprio(0);                                   \
  } while (0)
#define VMW0 asm volatile("s_waitcnt vmcnt(0)" ::: "memory")
#define BAR  __builtin_amdgcn_s_barrier()

  // prologue: stage step 0 into buf 0
  STAGE_(0, 0);
  VMW0;
  BAR;

  // 127 pipelined steps: 63 x (buf0, buf1) + 1 x buf0; tail reads buf1.
  for (int t = 0; t < NSTEP - 2; t += 2) {
    STAGE_(1, (t + 1) * 32);
    LDFRAG_(0); MM_();
    VMW0; BAR;
    STAGE_(0, (t + 2) * 32);
    LDFRAG_(1); MM_();
    VMW0; BAR;
  }
  STAGE_(1, (NSTEP - 1) * 32);
  LDFRAG_(0); MM_();
  VMW0; BAR;
  LDFRAG_(1); MM_();

#undef STAGE_
#undef LDFRAG_
#undef MM_
#undef VMW0
#undef BAR

  // C write: C/D layout col = lane&15, row = (lane>>4)*4 + reg
  float bb[4];
#pragma unroll
  for (int n = 0; n < 4; ++n) bb[n] = bias[bn * 128 + wn * 64 + n * 16 + l15];

  float* Cp = C + (size_t)(bm * 256 + wm * 64) * N_DIM + bn * 128 + wn * 64;
  const int rbase = (lane >> 4) * 4;
#pragma unroll
  for (int mi = 0; mi < 4; ++mi)
#pragma unroll
    for (int rr = 0; rr < 4; ++rr) {
      float* cr = Cp + (size_t)(mi * 16 + rbase + rr) * N_DIM;
#pragma unroll
      for (int n = 0; n < 4; ++n)
        cr[n * 16 + l15] = acc[mi][n][rr] + bb[n];
    }
}

// --------------------------- naive fallback (ws too small) ------------------
__global__ void naive_kernel(const float* __restrict__ x,
                             const float* __restrict__ cent,
                             const int* __restrict__ labels,
                             const float* __restrict__ bias,
                             float* __restrict__ out, int M) {
  __shared__ float cb[256];
  if (threadIdx.x < 256) cb[threadIdx.x] = cent[threadIdx.x];
  __syncthreads();
  long o = (long)blockIdx.x * blockDim.x + threadIdx.x;
  if (o >= (long)M * N_DIM) return;
  int n = (int)(o % N_DIM);
  long m = o / N_DIM;
  const float* xr = x + m * K_DIM;
  const int* lr = labels + (long)n * K_DIM;
  float s = 0.f;
  for (int k = 0; k < K_DIM; ++k) s += xr[k] * cb[lr[k]];
  out[o] = s + bias[n];
}

// ---------------------------------------------------------------------------
extern "C" void kernel_launch(void* const* d_in, const int* in_sizes, int n_in,
                              void* d_out, int out_size, void* d_ws, size_t ws_size,
                              hipStream_t stream) {
  const float* x      = (const float*)d_in[0];
  const float* cent   = (const float*)d_in[1];
  const int*   labels = (const int*)d_in[2];
  const float* bias   = (const float*)d_in[3];
  float* out = (float*)d_out;

  const int xN = in_sizes[0];      // M*K
  const int M  = xN / K_DIM;       // 8192
  const int wN = in_sizes[2];      // N*K

  const size_t need = (size_t)wN * 2 + (size_t)xN * 2;  // 96 MB
  if (ws_size < need || (M % 256) != 0) {
    long total = (long)M * N_DIM;
    int blocks = (int)((total + 255) / 256);
    naive_kernel<<<blocks, 256, 0, stream>>>(x, cent, labels, bias, out, M);
    return;
  }

  ushort* wb = (ushort*)d_ws;      // [N][K] bf16
  ushort* xb = wb + (size_t)wN;    // [M][K] bf16

  dequant_w<<<2048, 256, 0, stream>>>(labels, cent, wb, wN);
  cvt_x<<<2048, 256, 0, stream>>>(x, xb, xN);

  const int grid = (M / 256) * (N_DIM / 128);  // 1024
  gemm2<<<grid, 512, 0, stream>>>(xb, wb, bias, out);
}